// Round 1
// baseline (39.837 us; speedup 1.0000x reference)
//
#include <hip/hip_runtime.h>

// y[t][o] = sum_e cos(x[t][e] + theta[e]) * w[o][e]
// tokens = 128*8192 = 1048576, E = 16.

constexpr int E = 16;
constexpr int TPT = 2;          // tokens per thread
constexpr int BLOCK = 256;
constexpr long long NTOK = 128LL * 8192LL;   // 1048576

__global__ __launch_bounds__(BLOCK) void mhaq_kernel(
    const float* __restrict__ x,
    const float* __restrict__ theta,
    const float* __restrict__ w,     // [o][e] row-major
    float* __restrict__ y)
{
    __shared__ float ws[E * E];
    __shared__ float ths[E];

    const int tid = threadIdx.x;
    if (tid < E * E) ws[tid] = w[tid];
    if (tid < E)     ths[tid] = theta[tid];
    __syncthreads();

    // Block handles BLOCK*TPT consecutive tokens; thread's tokens are
    // base+tid and base+tid+BLOCK (keeps each float4 load wave-contiguous-ish).
    const long long base = (long long)blockIdx.x * (BLOCK * TPT) + tid;

    float z[TPT][E];
    #pragma unroll
    for (int k = 0; k < TPT; ++k) {
        const long long tok = base + (long long)k * BLOCK;
        const float4* xp = reinterpret_cast<const float4*>(x + tok * E);
        #pragma unroll
        for (int q = 0; q < 4; ++q) {
            float4 v = xp[q];
            z[k][q * 4 + 0] = __cosf(v.x + ths[q * 4 + 0]);
            z[k][q * 4 + 1] = __cosf(v.y + ths[q * 4 + 1]);
            z[k][q * 4 + 2] = __cosf(v.z + ths[q * 4 + 2]);
            z[k][q * 4 + 3] = __cosf(v.w + ths[q * 4 + 3]);
        }
    }

    float acc[TPT][E];
    #pragma unroll
    for (int k = 0; k < TPT; ++k)
        #pragma unroll
        for (int o = 0; o < E; ++o)
            acc[k][o] = 0.0f;

    #pragma unroll
    for (int o = 0; o < E; ++o) {
        #pragma unroll
        for (int q = 0; q < 4; ++q) {
            const float4 wv = *reinterpret_cast<const float4*>(&ws[o * E + q * 4]);
            #pragma unroll
            for (int k = 0; k < TPT; ++k) {
                acc[k][o] += z[k][q * 4 + 0] * wv.x
                           + z[k][q * 4 + 1] * wv.y
                           + z[k][q * 4 + 2] * wv.z
                           + z[k][q * 4 + 3] * wv.w;
            }
        }
    }

    #pragma unroll
    for (int k = 0; k < TPT; ++k) {
        const long long tok = base + (long long)k * BLOCK;
        float4* yp = reinterpret_cast<float4*>(y + tok * E);
        #pragma unroll
        for (int q = 0; q < 4; ++q) {
            yp[q] = make_float4(acc[k][q * 4 + 0], acc[k][q * 4 + 1],
                                acc[k][q * 4 + 2], acc[k][q * 4 + 3]);
        }
    }
}

extern "C" void kernel_launch(void* const* d_in, const int* in_sizes, int n_in,
                              void* d_out, int out_size, void* d_ws, size_t ws_size,
                              hipStream_t stream) {
    const float* x     = (const float*)d_in[0];
    const float* theta = (const float*)d_in[1];
    const float* w_out = (const float*)d_in[2];
    float* y = (float*)d_out;

    const int tokens_per_block = BLOCK * TPT;                 // 512
    const int grid = (int)(NTOK / tokens_per_block);          // 2048, exact
    mhaq_kernel<<<grid, BLOCK, 0, stream>>>(x, theta, w_out, y);
}

// Round 2
// 28.511 us; speedup vs baseline: 1.3972x; 1.3972x over previous
//
#include <hip/hip_runtime.h>

// y[t][o] = sum_e cos(x[t][e] + theta[e]) * w[o][e]
// tokens = 128*8192 = 1048576, E = 16.
//
// Cooperative layout: one float4 "slot" per lane per iteration.
// slot idx -> token = idx>>2, quarter q = idx&3. Blocks/lanes aligned so
// q == lane&3 (constant per thread) and each aligned 4-lane quad shares a token.
// Loads/stores are 16B/lane fully coalesced. z-exchange via quad shfl_xor.

constexpr int E = 16;
constexpr int BLOCK = 256;
constexpr int J = 4;                         // float4 slots per thread
constexpr long long NTOK = 128LL * 8192LL;   // 1048576
constexpr long long NSLOT = NTOK * 4;        // 4194304 float4 slots

__global__ __launch_bounds__(BLOCK) void mhaq_kernel(
    const float4* __restrict__ x4,
    const float* __restrict__ theta,
    const float* __restrict__ w,     // [o][e] row-major, 16x16
    float4* __restrict__ y4)
{
    __shared__ float ws[E * E];

    const int tid = threadIdx.x;
    ws[tid] = w[tid];                // BLOCK == 256 == E*E exactly
    __syncthreads();

    const int q = tid & 3;           // my quarter (element block) within token
    const float4 th = reinterpret_cast<const float4*>(theta)[q];

    const long long base = (long long)blockIdx.x * (BLOCK * J) + tid;

    // issue all loads up-front (4 in flight per lane)
    float4 v[J];
    #pragma unroll
    for (int j = 0; j < J; ++j)
        v[j] = x4[base + (long long)j * BLOCK];

    #pragma unroll
    for (int j = 0; j < J; ++j) {
        // my 4 z values: e = 4q + k
        float zb[4][4];              // zb[d][k] = z of lane^d (quarter q^d)
        zb[0][0] = __cosf(v[j].x + th.x);
        zb[0][1] = __cosf(v[j].y + th.y);
        zb[0][2] = __cosf(v[j].z + th.z);
        zb[0][3] = __cosf(v[j].w + th.w);

        #pragma unroll
        for (int d = 1; d < 4; ++d) {
            #pragma unroll
            for (int k = 0; k < 4; ++k)
                zb[d][k] = __shfl_xor(zb[0][k], d, 4);
        }

        // my 4 outputs: o = 4q + oo
        float acc0 = 0.f, acc1 = 0.f, acc2 = 0.f, acc3 = 0.f;
        #pragma unroll
        for (int d = 0; d < 4; ++d) {
            const int eb = q ^ d;    // element block held in zb[d]
            const float* wrow = &ws[(q * 4) * E + eb * 4];
            const float4 w0 = *reinterpret_cast<const float4*>(wrow + 0 * E);
            const float4 w1 = *reinterpret_cast<const float4*>(wrow + 1 * E);
            const float4 w2 = *reinterpret_cast<const float4*>(wrow + 2 * E);
            const float4 w3 = *reinterpret_cast<const float4*>(wrow + 3 * E);
            acc0 += zb[d][0] * w0.x + zb[d][1] * w0.y + zb[d][2] * w0.z + zb[d][3] * w0.w;
            acc1 += zb[d][0] * w1.x + zb[d][1] * w1.y + zb[d][2] * w1.z + zb[d][3] * w1.w;
            acc2 += zb[d][0] * w2.x + zb[d][1] * w2.y + zb[d][2] * w2.z + zb[d][3] * w2.w;
            acc3 += zb[d][0] * w3.x + zb[d][1] * w3.y + zb[d][2] * w3.z + zb[d][3] * w3.w;
        }

        y4[base + (long long)j * BLOCK] = make_float4(acc0, acc1, acc2, acc3);
    }
}

extern "C" void kernel_launch(void* const* d_in, const int* in_sizes, int n_in,
                              void* d_out, int out_size, void* d_ws, size_t ws_size,
                              hipStream_t stream) {
    const float4* x4   = (const float4*)d_in[0];
    const float* theta = (const float*)d_in[1];
    const float* w_out = (const float*)d_in[2];
    float4* y4 = (float4*)d_out;

    const int grid = (int)(NSLOT / (BLOCK * J));   // 4096, exact
    mhaq_kernel<<<grid, BLOCK, 0, stream>>>(x4, theta, w_out, y4);
}

// Round 3
// 26.232 us; speedup vs baseline: 1.5186x; 1.0869x over previous
//
#include <hip/hip_runtime.h>

// y[t][o] = sum_e cos(x[t][e] + theta[e]) * w[o][e]
// tokens = 128*8192 = 1048576, E = 16.
//
// Slot layout: one float4 per lane per iteration; quarter q = tid&3 constant
// per thread; aligned 4-lane quads share a token. Coalesced 16B/lane ld/st.
// z exchanged via quad shfl_xor (DPP). Weights held in 64 VGPRs per lane,
// loaded from LDS ONCE (they were 64 ds_read_b128/thread in the inner loop
// before — LDS pipe was co-saturated with HBM).

constexpr int E = 16;
constexpr int BLOCK = 256;
constexpr int J = 4;                         // float4 slots per thread
constexpr long long NTOK = 128LL * 8192LL;   // 1048576
constexpr long long NSLOT = NTOK * 4;        // 4194304 float4 slots

__global__ __launch_bounds__(BLOCK) void mhaq_kernel(
    const float4* __restrict__ x4,
    const float* __restrict__ theta,
    const float* __restrict__ w,     // [o][e] row-major, 16x16
    float4* __restrict__ y4)
{
    __shared__ float ws[E * E];

    const int tid = threadIdx.x;
    ws[tid] = w[tid];                // BLOCK == 256 == E*E exactly
    __syncthreads();

    const int q = tid & 3;           // my quarter (element block) within token
    const float4 th = reinterpret_cast<const float4*>(theta)[q];

    const long long base = (long long)blockIdx.x * (BLOCK * J) + tid;

    // issue all x loads up-front (4 in flight per lane)
    float4 v[J];
    #pragma unroll
    for (int j = 0; j < J; ++j)
        v[j] = x4[base + (long long)j * BLOCK];

    // Hoisted weights: wq[oo][d] = W row (4q+oo), element chunk (q^d).
    // All register indices compile-time (oo,d unrolled) -> stays in VGPRs.
    float4 wq[4][4];
    #pragma unroll
    for (int oo = 0; oo < 4; ++oo) {
        #pragma unroll
        for (int d = 0; d < 4; ++d) {
            wq[oo][d] = *reinterpret_cast<const float4*>(
                &ws[(4 * q + oo) * E + ((q ^ d) * 4)]);
        }
    }

    #pragma unroll
    for (int j = 0; j < J; ++j) {
        // my 4 z values: e = 4q + k
        float zb[4][4];              // zb[d][k] = z of lane^d (quarter q^d)
        zb[0][0] = __cosf(v[j].x + th.x);
        zb[0][1] = __cosf(v[j].y + th.y);
        zb[0][2] = __cosf(v[j].z + th.z);
        zb[0][3] = __cosf(v[j].w + th.w);

        #pragma unroll
        for (int d = 1; d < 4; ++d) {
            #pragma unroll
            for (int k = 0; k < 4; ++k)
                zb[d][k] = __shfl_xor(zb[0][k], d, 4);
        }

        // my 4 outputs: o = 4q + oo; zb[d] holds element chunk (q^d)
        float acc0 = 0.f, acc1 = 0.f, acc2 = 0.f, acc3 = 0.f;
        #pragma unroll
        for (int d = 0; d < 4; ++d) {
            acc0 += zb[d][0] * wq[0][d].x + zb[d][1] * wq[0][d].y
                  + zb[d][2] * wq[0][d].z + zb[d][3] * wq[0][d].w;
            acc1 += zb[d][0] * wq[1][d].x + zb[d][1] * wq[1][d].y
                  + zb[d][2] * wq[1][d].z + zb[d][3] * wq[1][d].w;
            acc2 += zb[d][0] * wq[2][d].x + zb[d][1] * wq[2][d].y
                  + zb[d][2] * wq[2][d].z + zb[d][3] * wq[2][d].w;
            acc3 += zb[d][0] * wq[3][d].x + zb[d][1] * wq[3][d].y
                  + zb[d][2] * wq[3][d].z + zb[d][3] * wq[3][d].w;
        }

        y4[base + (long long)j * BLOCK] = make_float4(acc0, acc1, acc2, acc3);
    }
}

extern "C" void kernel_launch(void* const* d_in, const int* in_sizes, int n_in,
                              void* d_out, int out_size, void* d_ws, size_t ws_size,
                              hipStream_t stream) {
    const float4* x4   = (const float4*)d_in[0];
    const float* theta = (const float*)d_in[1];
    const float* w_out = (const float*)d_in[2];
    float4* y4 = (float4*)d_out;

    const int grid = (int)(NSLOT / (BLOCK * J));   // 4096, exact
    mhaq_kernel<<<grid, BLOCK, 0, stream>>>(x4, theta, w_out, y4);
}

// Round 5
// 25.508 us; speedup vs baseline: 1.5617x; 1.0284x over previous
//
#include <hip/hip_runtime.h>

// y[t][o] = sum_e cos(x[t][e] + theta[e]) * w[o][e]
// tokens = 128*8192 = 1048576, E = 16.
//
// Slot layout: one float4 per lane per iteration; quarter q = tid&3 constant
// per thread; aligned 4-lane quads share a token. Coalesced 16B/lane ld/st.
// z exchanged via quad shfl_xor (DPP). Weights held in 64 VGPRs per lane,
// loaded from LDS once.
// Round 4/5: y stored non-temporally (nt) so the write stream doesn't
// allocate in L2/L3 -> x (67 MB) stays Infinity-Cache-resident across replays
// -> HBM becomes a near-write-only stream (~6.9 TB/s per fill-kernel evidence).
// nt store must use a native vector type, not HIP_vector_type.

typedef float floatx4 __attribute__((ext_vector_type(4)));

constexpr int E = 16;
constexpr int BLOCK = 256;
constexpr int J = 4;                         // float4 slots per thread
constexpr long long NTOK = 128LL * 8192LL;   // 1048576
constexpr long long NSLOT = NTOK * 4;        // 4194304 float4 slots

__global__ __launch_bounds__(BLOCK) void mhaq_kernel(
    const float4* __restrict__ x4,
    const float* __restrict__ theta,
    const float* __restrict__ w,     // [o][e] row-major, 16x16
    floatx4* __restrict__ y4)
{
    __shared__ float ws[E * E];

    const int tid = threadIdx.x;
    ws[tid] = w[tid];                // BLOCK == 256 == E*E exactly
    __syncthreads();

    const int q = tid & 3;           // my quarter (element block) within token
    const float4 th = reinterpret_cast<const float4*>(theta)[q];

    const long long base = (long long)blockIdx.x * (BLOCK * J) + tid;

    // issue all x loads up-front (4 in flight per lane)
    float4 v[J];
    #pragma unroll
    for (int j = 0; j < J; ++j)
        v[j] = x4[base + (long long)j * BLOCK];

    // Hoisted weights: wq[oo][d] = W row (4q+oo), element chunk (q^d).
    float4 wq[4][4];
    #pragma unroll
    for (int oo = 0; oo < 4; ++oo) {
        #pragma unroll
        for (int d = 0; d < 4; ++d) {
            wq[oo][d] = *reinterpret_cast<const float4*>(
                &ws[(4 * q + oo) * E + ((q ^ d) * 4)]);
        }
    }

    #pragma unroll
    for (int j = 0; j < J; ++j) {
        // my 4 z values: e = 4q + k
        float zb[4][4];              // zb[d][k] = z of lane^d (quarter q^d)
        zb[0][0] = __cosf(v[j].x + th.x);
        zb[0][1] = __cosf(v[j].y + th.y);
        zb[0][2] = __cosf(v[j].z + th.z);
        zb[0][3] = __cosf(v[j].w + th.w);

        #pragma unroll
        for (int d = 1; d < 4; ++d) {
            #pragma unroll
            for (int k = 0; k < 4; ++k)
                zb[d][k] = __shfl_xor(zb[0][k], d, 4);
        }

        // my 4 outputs: o = 4q + oo; zb[d] holds element chunk (q^d)
        float acc0 = 0.f, acc1 = 0.f, acc2 = 0.f, acc3 = 0.f;
        #pragma unroll
        for (int d = 0; d < 4; ++d) {
            acc0 += zb[d][0] * wq[0][d].x + zb[d][1] * wq[0][d].y
                  + zb[d][2] * wq[0][d].z + zb[d][3] * wq[0][d].w;
            acc1 += zb[d][0] * wq[1][d].x + zb[d][1] * wq[1][d].y
                  + zb[d][2] * wq[1][d].z + zb[d][3] * wq[1][d].w;
            acc2 += zb[d][0] * wq[2][d].x + zb[d][1] * wq[2][d].y
                  + zb[d][2] * wq[2][d].z + zb[d][3] * wq[2][d].w;
            acc3 += zb[d][0] * wq[3][d].x + zb[d][1] * wq[3][d].y
                  + zb[d][2] * wq[3][d].z + zb[d][3] * wq[3][d].w;
        }

        floatx4 out;
        out.x = acc0; out.y = acc1; out.z = acc2; out.w = acc3;
        __builtin_nontemporal_store(out, &y4[base + (long long)j * BLOCK]);
    }
}

extern "C" void kernel_launch(void* const* d_in, const int* in_sizes, int n_in,
                              void* d_out, int out_size, void* d_ws, size_t ws_size,
                              hipStream_t stream) {
    const float4* x4   = (const float4*)d_in[0];
    const float* theta = (const float*)d_in[1];
    const float* w_out = (const float*)d_in[2];
    floatx4* y4 = (floatx4*)d_out;

    const int grid = (int)(NSLOT / (BLOCK * J));   // 4096, exact
    mhaq_kernel<<<grid, BLOCK, 0, stream>>>(x4, theta, w_out, y4);
}